// Round 5
// baseline (60.851 us; speedup 1.0000x reference)
//
#include <hip/hip_runtime.h>

#define B 4
#define P 1024
#define M 12
#define N 256
#define L 512
#define D 256
#define DC 256
#define FEA 1064          // 2*D + 20 + 20 + 2*DC
#define ROWS (B * P * M)  // 49152
#define NBLK 2048         // persistent blocks for stream kernel

typedef float f32x4 __attribute__((ext_vector_type(4)));

// ---------------- setup: per-row descriptor + mask ----------------
__global__ __launch_bounds__(256) void setup_kernel(
    const int* __restrict__ rel,    // [B,P,M,4]
    const int* __restrict__ pinfo,  // [B,N,6]
    float* __restrict__ out,        // mask goes to out[ROWS*FEA + row]
    int* __restrict__ ws)           // [ROWS][8] descriptors
{
    const int row = blockIdx.x * 256 + threadIdx.x;
    if (row >= ROWS) return;
    const int b = row / (P * M);
    const int m = row % M;
    const int branch = m >> 2;

    const int4 sel = *reinterpret_cast<const int4*>(rel + (size_t)row * 4);
    const int zf = (sel.x + sel.y + sel.z + sel.w) > 0;
    const int ia = sel.x;
    const int ib = (branch == 0) ? sel.z : sel.w;
    const int logical = (branch == 2);

    const int* pbase = pinfo + b * N * 6;      // pos[n] = pbase[n*6]
    const int pos_ia = pbase[ia * 6];
    const int pos_ib = pbase[ib * 6];
    const int delta = pos_ia - pos_ib;
    const int u = delta & 511;                  // jnp.mod(delta, 512)
    const int d2 = (u == 0) ? 0 : (32 - __clz(u));
    const int idx = (delta < 0) ? (10 - d2) : (10 + d2);

    const int s0 = pbase[sel.x * 6];
    const int s2 = pbase[sel.z * 6];
    const int s1 = logical ? pbase[sel.y * 6] : 0;
    const int s3 = logical ? pbase[sel.w * 6] : 0;

    int4 da, db;
    da.x = (b * N + ia) * D;                    // gf elem offset A
    da.y = (b * N + ib) * D;                    // gf elem offset B
    da.z = idx * 20;                            // emb table elem offset
    da.w = (logical ? 1 : 0) | (zf ? 2 : 0);    // flags
    const int cb = b * L * DC;
    db.x = cb + s0 * DC;
    db.y = cb + s1 * DC;
    db.z = cb + s2 * DC;
    db.w = cb + s3 * DC;

    reinterpret_cast<int4*>(ws)[(size_t)row * 2]     = da;
    reinterpret_cast<int4*>(ws)[(size_t)row * 2 + 1] = db;

    const bool rm = (sel.x > 0) || (sel.y > 0) || (sel.z > 0) || (sel.w > 0);
    out[(size_t)ROWS * FEA + row] = rm ? 1.0f : 0.0f;
}

// ---------------- stream: gather + concat + store ----------------
struct RV { f32x4 v0, v1, v2, v3, v4; };

__device__ __forceinline__ RV load_row(int row, int lane,
                                       const float* __restrict__ gf,
                                       const float* __restrict__ cf,
                                       const float* __restrict__ dw,
                                       const float* __restrict__ sw,
                                       const int* __restrict__ ws)
{
    const int4 da = reinterpret_cast<const int4*>(ws)[(size_t)row * 2];
    const int4 db = reinterpret_cast<const int4*>(ws)[(size_t)row * 2 + 1];
    const bool logical = (da.w & 1);
    const float zf = (da.w & 2) ? 1.0f : 0.0f;

    const f32x4* gA  = reinterpret_cast<const f32x4*>(gf + da.x);
    const f32x4* gB  = reinterpret_cast<const f32x4*>(gf + da.y);
    const f32x4* dwr = reinterpret_cast<const f32x4*>(dw + da.z);
    const f32x4* swr = reinterpret_cast<const f32x4*>(sw + da.z);
    const f32x4* c0  = reinterpret_cast<const f32x4*>(cf + db.x);
    const f32x4* c1  = reinterpret_cast<const f32x4*>(cf + db.y);
    const f32x4* c2  = reinterpret_cast<const f32x4*>(cf + db.z);
    const f32x4* c3  = reinterpret_cast<const f32x4*>(cf + db.w);

    RV r;
    r.v0 = gA[lane];                            // f4[0,64)   rep A
    r.v1 = gB[lane];                            // f4[64,128) rep B
    r.v4 = (f32x4){0.f, 0.f, 0.f, 0.f};
    // f4[128,192): 5 emb + 5 semb + c0[0..53]
    if (lane < 5)       r.v2 = dwr[lane];
    else if (lane < 10) r.v2 = swr[lane - 5];
    else {              r.v2 = c0[lane - 10]; if (logical) r.v2 += c1[lane - 10]; }
    // f4[192,256): c0[54..63] + c2[0..53]
    if (lane < 10) {    r.v3 = c0[54 + lane]; if (logical) r.v3 += c1[54 + lane]; }
    else {              r.v3 = c2[lane - 10]; if (logical) r.v3 += c3[lane - 10]; }
    // f4[256,266): c2[54..63] (lanes 0..9 only)
    if (lane < 10) {    r.v4 = c2[54 + lane]; if (logical) r.v4 += c3[54 + lane]; }

    r.v0 *= zf; r.v1 *= zf; r.v2 *= zf; r.v3 *= zf; r.v4 *= zf;
    return r;
}

__device__ __forceinline__ void store_row(int row, int lane, float* __restrict__ out,
                                          const RV& r)
{
    f32x4* orow = reinterpret_cast<f32x4*>(out + (size_t)row * FEA);
    __builtin_nontemporal_store(r.v0, &orow[lane]);
    __builtin_nontemporal_store(r.v1, &orow[64 + lane]);
    __builtin_nontemporal_store(r.v2, &orow[128 + lane]);
    __builtin_nontemporal_store(r.v3, &orow[192 + lane]);
    if (lane < 10) __builtin_nontemporal_store(r.v4, &orow[256 + lane]);
}

__global__ __launch_bounds__(256) void stream_kernel(
    const float* __restrict__ gf,   // [B,N,D]
    const float* __restrict__ cf,   // [B,L,DC]
    const float* __restrict__ dw,   // [20,20]
    const float* __restrict__ sw,   // [20,20]
    const int* __restrict__ ws,     // [ROWS][8]
    float* __restrict__ out)        // [ROWS*FEA]
{
    const int lane  = threadIdx.x & 63;
    const int gwave = (blockIdx.x * 256 + threadIdx.x) >> 6;
    const int nwav  = NBLK * 4;

    // 2 adjacent rows per iteration: deep MLP + contiguous 8.5KB store span.
    for (int r = 2 * gwave; r < ROWS; r += 2 * nwav) {
        const int ra = __builtin_amdgcn_readfirstlane(r);
        const int rb = ra + 1;

        RV va = load_row(ra, lane, gf, cf, dw, sw, ws);
        RV vb = load_row(rb, lane, gf, cf, dw, sw, ws);

        store_row(ra, lane, out, va);
        store_row(rb, lane, out, vb);
    }
}

extern "C" void kernel_launch(void* const* d_in, const int* in_sizes, int n_in,
                              void* d_out, int out_size, void* d_ws, size_t ws_size,
                              hipStream_t stream) {
    const int*   rel   = (const int*)d_in[0];
    const int*   pinfo = (const int*)d_in[1];
    const float* gf    = (const float*)d_in[2];
    const float* cf    = (const float*)d_in[3];
    const float* dw    = (const float*)d_in[4];
    const float* sw    = (const float*)d_in[5];
    float* out = (float*)d_out;
    int*   ws  = (int*)d_ws;

    setup_kernel<<<(ROWS + 255) / 256, 256, 0, stream>>>(rel, pinfo, out, ws);
    stream_kernel<<<NBLK, 256, 0, stream>>>(gf, cf, dw, sw, ws, out);
}

// Round 6
// 54.990 us; speedup vs baseline: 1.1066x; 1.1066x over previous
//
#include <hip/hip_runtime.h>

#define B 4
#define P 1024
#define M 12
#define N 256
#define L 512
#define D 256
#define DC 256
#define FEA 1064          // 2*D + 20 + 20 + 2*DC
#define ROWS (B * P * M)  // 49152
#define NBLK 2048         // persistent blocks for stream kernel

typedef float f32x4 __attribute__((ext_vector_type(4)));

// ---------------- setup: per-row descriptor + mask ----------------
__global__ __launch_bounds__(256) void setup_kernel(
    const int* __restrict__ rel,    // [B,P,M,4]
    const int* __restrict__ pinfo,  // [B,N,6]
    float* __restrict__ out,        // mask goes to out[ROWS*FEA + row]
    int* __restrict__ ws)           // [ROWS][8] descriptors
{
    const int row = blockIdx.x * 256 + threadIdx.x;
    if (row >= ROWS) return;
    const int b = row / (P * M);
    const int m = row % M;
    const int branch = m >> 2;

    const int4 sel = *reinterpret_cast<const int4*>(rel + (size_t)row * 4);
    const int zf = (sel.x + sel.y + sel.z + sel.w) > 0;
    const int ia = sel.x;
    const int ib = (branch == 0) ? sel.z : sel.w;
    const int logical = (branch == 2);

    const int* pbase = pinfo + b * N * 6;      // pos[n] = pbase[n*6]
    const int pos_ia = pbase[ia * 6];
    const int pos_ib = pbase[ib * 6];
    const int delta = pos_ia - pos_ib;
    const int u = delta & 511;                  // jnp.mod(delta, 512)
    const int d2 = (u == 0) ? 0 : (32 - __clz(u));
    const int idx = (delta < 0) ? (10 - d2) : (10 + d2);

    const int s0 = pbase[sel.x * 6];
    const int s2 = pbase[sel.z * 6];
    const int s1 = logical ? pbase[sel.y * 6] : 0;
    const int s3 = logical ? pbase[sel.w * 6] : 0;

    int4 da, db;
    da.x = (b * N + ia) * D;                    // gf elem offset A
    da.y = (b * N + ib) * D;                    // gf elem offset B
    da.z = idx * 20;                            // emb table elem offset
    da.w = (logical ? 1 : 0) | (zf ? 2 : 0);    // flags
    const int cb = b * L * DC;
    db.x = cb + s0 * DC;
    db.y = cb + s1 * DC;
    db.z = cb + s2 * DC;
    db.w = cb + s3 * DC;

    reinterpret_cast<int4*>(ws)[(size_t)row * 2]     = da;
    reinterpret_cast<int4*>(ws)[(size_t)row * 2 + 1] = db;

    const bool rm = (sel.x > 0) || (sel.y > 0) || (sel.z > 0) || (sel.w > 0);
    out[(size_t)ROWS * FEA + row] = rm ? 1.0f : 0.0f;
}

// ---------------- stream: gather + concat + store ----------------
__global__ __launch_bounds__(256) void stream_kernel(
    const float* __restrict__ gf,   // [B,N,D]
    const float* __restrict__ cf,   // [B,L,DC]
    const float* __restrict__ dw,   // [20,20]
    const float* __restrict__ sw,   // [20,20]
    const int* __restrict__ ws,     // [ROWS][8]
    float* __restrict__ out)        // [ROWS*FEA]
{
    const int lane  = threadIdx.x & 63;
    const int gwave = (blockIdx.x * 256 + threadIdx.x) >> 6;
    const int nwav  = NBLK * 4;

    for (int r = gwave; r < ROWS; r += nwav) {
        const int row = __builtin_amdgcn_readfirstlane(r);  // force uniform → s_load bases

        const int4 da = reinterpret_cast<const int4*>(ws)[(size_t)row * 2];
        const int4 db = reinterpret_cast<const int4*>(ws)[(size_t)row * 2 + 1];
        const bool logical = (da.w & 1);
        const float zf = (da.w & 2) ? 1.0f : 0.0f;

        const f32x4* gA  = reinterpret_cast<const f32x4*>(gf + da.x);
        const f32x4* gB  = reinterpret_cast<const f32x4*>(gf + da.y);
        const f32x4* dwr = reinterpret_cast<const f32x4*>(dw + da.z);
        const f32x4* swr = reinterpret_cast<const f32x4*>(sw + da.z);
        const f32x4* c0  = reinterpret_cast<const f32x4*>(cf + db.x);
        const f32x4* c1  = reinterpret_cast<const f32x4*>(cf + db.y);
        const f32x4* c2  = reinterpret_cast<const f32x4*>(cf + db.z);
        const f32x4* c3  = reinterpret_cast<const f32x4*>(cf + db.w);

        // Issue ALL row loads before any store (max MLP).
        f32x4 v0 = gA[lane];                        // f4[0,64)   rep A
        f32x4 v1 = gB[lane];                        // f4[64,128) rep B
        f32x4 v2, v3, v4 = {0.f, 0.f, 0.f, 0.f};
        // f4[128,192): 5 emb + 5 semb + c0[0..53]
        if (lane < 5)       v2 = dwr[lane];
        else if (lane < 10) v2 = swr[lane - 5];
        else {              v2 = c0[lane - 10]; if (logical) v2 += c1[lane - 10]; }
        // f4[192,256): c0[54..63] + c2[0..53]
        if (lane < 10) {    v3 = c0[54 + lane]; if (logical) v3 += c1[54 + lane]; }
        else {              v3 = c2[lane - 10]; if (logical) v3 += c3[lane - 10]; }
        // f4[256,266): c2[54..63] (lanes 0..9 only)
        if (lane < 10) {    v4 = c2[54 + lane]; if (logical) v4 += c3[54 + lane]; }

        v0 *= zf; v1 *= zf; v2 *= zf; v3 *= zf; v4 *= zf;

        f32x4* orow = reinterpret_cast<f32x4*>(out + (size_t)row * FEA);
        __builtin_nontemporal_store(v0, &orow[lane]);
        __builtin_nontemporal_store(v1, &orow[64 + lane]);
        __builtin_nontemporal_store(v2, &orow[128 + lane]);
        __builtin_nontemporal_store(v3, &orow[192 + lane]);
        if (lane < 10) __builtin_nontemporal_store(v4, &orow[256 + lane]);
    }
}

extern "C" void kernel_launch(void* const* d_in, const int* in_sizes, int n_in,
                              void* d_out, int out_size, void* d_ws, size_t ws_size,
                              hipStream_t stream) {
    const int*   rel   = (const int*)d_in[0];
    const int*   pinfo = (const int*)d_in[1];
    const float* gf    = (const float*)d_in[2];
    const float* cf    = (const float*)d_in[3];
    const float* dw    = (const float*)d_in[4];
    const float* sw    = (const float*)d_in[5];
    float* out = (float*)d_out;
    int*   ws  = (int*)d_ws;

    setup_kernel<<<(ROWS + 255) / 256, 256, 0, stream>>>(rel, pinfo, out, ws);
    stream_kernel<<<NBLK, 256, 0, stream>>>(gf, cf, dw, sw, ws, out);
}

// Round 7
// 42.962 us; speedup vs baseline: 1.4164x; 1.2800x over previous
//
#include <hip/hip_runtime.h>

#define B 4
#define P 1024
#define M 12
#define N 256
#define L 512
#define D 256
#define DC 256
#define FEA 1064          // 2*D + 20 + 20 + 2*DC
#define ROWS (B * P * M)  // 49152
#define NBLK 2048         // persistent blocks

typedef float f32x4 __attribute__((ext_vector_type(4)));

__global__ __launch_bounds__(256) void fused_kernel(
    const int* __restrict__ rel,    // [B,P,M,4]
    const int* __restrict__ pinfo,  // [B,N,6]
    const float* __restrict__ gf,   // [B,N,D]
    const float* __restrict__ cf,   // [B,L,DC]
    const float* __restrict__ dw,   // [20,20]
    const float* __restrict__ sw,   // [20,20]
    float* __restrict__ out)        // [ROWS*FEA] fea ++ [ROWS] mask
{
    const int lane  = threadIdx.x & 63;
    const int gwave = (blockIdx.x * 256 + threadIdx.x) >> 6;
    const int nwav  = NBLK * 4;

    for (int r = gwave; r < ROWS; r += nwav) {
        const int row = __builtin_amdgcn_readfirstlane(r);

        // ---- descriptor math, wave-redundant (all L1-hit tiny loads) ----
        const int b = row / (P * M);
        const int m = row % M;
        const int branch = m >> 2;

        const int4 sel = *reinterpret_cast<const int4*>(rel + (size_t)row * 4);
        const float zf = ((sel.x + sel.y + sel.z + sel.w) > 0) ? 1.0f : 0.0f;
        const int ia = sel.x;
        const int ib = (branch == 0) ? sel.z : sel.w;
        const bool logical = (branch == 2);

        const int* pbase = pinfo + b * N * 6;     // pos[n] = pbase[n*6]
        const int pos_ia = pbase[ia * 6];
        const int pos_ib = pbase[ib * 6];
        const int delta = pos_ia - pos_ib;
        const int u = delta & 511;                 // jnp.mod(delta, 512)
        const int d2 = (u == 0) ? 0 : (32 - __clz(u));
        const int idx = (delta < 0) ? (10 - d2) : (10 + d2);

        const int s0 = pbase[sel.x * 6];
        const int s2 = pbase[sel.z * 6];
        const int s1 = logical ? pbase[sel.y * 6] : 0;
        const int s3 = logical ? pbase[sel.w * 6] : 0;

        const int cb = b * L * DC;
        // Force computed offsets into SGPRs → scalar base + lane offset addressing.
        const int offA  = __builtin_amdgcn_readfirstlane((b * N + ia) * D);
        const int offB  = __builtin_amdgcn_readfirstlane((b * N + ib) * D);
        const int offE  = __builtin_amdgcn_readfirstlane(idx * 20);
        const int off0  = __builtin_amdgcn_readfirstlane(cb + s0 * DC);
        const int off1  = __builtin_amdgcn_readfirstlane(cb + s1 * DC);
        const int off2  = __builtin_amdgcn_readfirstlane(cb + s2 * DC);
        const int off3  = __builtin_amdgcn_readfirstlane(cb + s3 * DC);

        const f32x4* gA  = reinterpret_cast<const f32x4*>(gf + offA);
        const f32x4* gB  = reinterpret_cast<const f32x4*>(gf + offB);
        const f32x4* dwr = reinterpret_cast<const f32x4*>(dw + offE);
        const f32x4* swr = reinterpret_cast<const f32x4*>(sw + offE);
        const f32x4* c0  = reinterpret_cast<const f32x4*>(cf + off0);
        const f32x4* c1  = reinterpret_cast<const f32x4*>(cf + off1);
        const f32x4* c2  = reinterpret_cast<const f32x4*>(cf + off2);
        const f32x4* c3  = reinterpret_cast<const f32x4*>(cf + off3);

        // ---- gather: issue all loads before any store ----
        f32x4 v0 = gA[lane];                        // f4[0,64)   rep A
        f32x4 v1 = gB[lane];                        // f4[64,128) rep B
        f32x4 v2, v3, v4 = {0.f, 0.f, 0.f, 0.f};
        // f4[128,192): 5 emb + 5 semb + c0[0..53]
        if (lane < 5)       v2 = dwr[lane];
        else if (lane < 10) v2 = swr[lane - 5];
        else {              v2 = c0[lane - 10]; if (logical) v2 += c1[lane - 10]; }
        // f4[192,256): c0[54..63] + c2[0..53]
        if (lane < 10) {    v3 = c0[54 + lane]; if (logical) v3 += c1[54 + lane]; }
        else {              v3 = c2[lane - 10]; if (logical) v3 += c3[lane - 10]; }
        // f4[256,266): c2[54..63] (lanes 0..9 only)
        if (lane < 10) {    v4 = c2[54 + lane]; if (logical) v4 += c3[54 + lane]; }

        v0 *= zf; v1 *= zf; v2 *= zf; v3 *= zf; v4 *= zf;

        f32x4* orow = reinterpret_cast<f32x4*>(out + (size_t)row * FEA);
        orow[lane]       = v0;
        orow[64 + lane]  = v1;
        orow[128 + lane] = v2;
        orow[192 + lane] = v3;
        if (lane < 10) orow[256 + lane] = v4;

        if (lane == 0) {
            const bool rm = (sel.x > 0) || (sel.y > 0) || (sel.z > 0) || (sel.w > 0);
            out[(size_t)ROWS * FEA + row] = rm ? 1.0f : 0.0f;
        }
    }
}

extern "C" void kernel_launch(void* const* d_in, const int* in_sizes, int n_in,
                              void* d_out, int out_size, void* d_ws, size_t ws_size,
                              hipStream_t stream) {
    const int*   rel   = (const int*)d_in[0];
    const int*   pinfo = (const int*)d_in[1];
    const float* gf    = (const float*)d_in[2];
    const float* cf    = (const float*)d_in[3];
    const float* dw    = (const float*)d_in[4];
    const float* sw    = (const float*)d_in[5];
    float* out = (float*)d_out;

    fused_kernel<<<NBLK, 256, 0, stream>>>(rel, pinfo, gf, cf, dw, sw, out);
}